// Round 13
// baseline (623.830 us; speedup 1.0000x reference)
//
#include <hip/hip_runtime.h>

typedef __attribute__((ext_vector_type(8))) __bf16 bf16x8;
typedef __attribute__((ext_vector_type(4))) __bf16 bf16x4;
typedef __attribute__((ext_vector_type(4))) float f32x4;
typedef unsigned long long ull;

static constexpr int kB = 4, kT = 2048, kD = 1024, kH = 16;
static constexpr int kC = 32000, kM = 8192, k3D = 3072, kQK = 2048;

#define MFMA16(a, b, c) __builtin_amdgcn_mfma_f32_16x16x32_bf16((a), (b), (c), 0, 0, 0)

__device__ __forceinline__ void gload_lds16(const __bf16* g, __bf16* l) {
  __builtin_amdgcn_global_load_lds(
      (const __attribute__((address_space(1))) unsigned int*)(const void*)g,
      (__attribute__((address_space(3))) unsigned int*)(void*)l, 16, 0, 0);
}

// ---------------- prep: merged weight transposes + fused embed/LN0 ----------------
__global__ __launch_bounds__(256) void prep_kernel(const float* __restrict__ qkv_W,
                                                   const float* __restrict__ out_W,
                                                   __bf16* __restrict__ WqkvT,
                                                   __bf16* __restrict__ WoT,
                                                   const int* __restrict__ tok,
                                                   const float* __restrict__ embW,
                                                   const float* __restrict__ posW,
                                                   const float* __restrict__ g,
                                                   const float* __restrict__ bb,
                                                   float* __restrict__ h,
                                                   __bf16* __restrict__ hn) {
  const int bid = blockIdx.x, tid = threadIdx.x;
  if (bid < 7168) {
    __shared__ float sh[32][33];
    const float* W; __bf16* WT; int N, tile;
    if (bid < 3072)      { W = qkv_W;                  WT = WqkvT;                  N = k3D; tile = bid; }
    else if (bid < 6144) { W = qkv_W + (size_t)kD*k3D; WT = WqkvT + (size_t)k3D*kD; N = k3D; tile = bid - 3072; }
    else                 { W = out_W;                  WT = WoT;                    N = kD;  tile = bid - 6144; }
    const int tx = tid & 31, ty = tid >> 5;
    const int ntile = N >> 5;
    const int c0 = (tile % ntile) << 5;
    const int r0 = (tile / ntile) << 5;
    #pragma unroll
    for (int i = 0; i < 4; i++) {
      const int r = ty + i * 8;
      sh[r][tx] = W[(size_t)(r0 + r) * N + c0 + tx];
    }
    __syncthreads();
    #pragma unroll
    for (int i = 0; i < 4; i++) {
      const int cc = ty + i * 8;
      WT[(size_t)(c0 + cc) * kD + r0 + tx] = (__bf16)sh[tx][cc];
    }
  } else {
    const int row = bid - 7168;
    const int t = row & (kT - 1);
    const int tk = tok[row];
    const f32x4 e = ((const f32x4*)(embW + (size_t)tk * kD))[tid];
    const f32x4 p = ((const f32x4*)(posW + (size_t)t * kD))[tid];
    const f32x4 xv = e + p;
    ((f32x4*)(h + (size_t)row * kD))[tid] = xv;
    float s  = xv[0] + xv[1] + xv[2] + xv[3];
    float s2 = xv[0]*xv[0] + xv[1]*xv[1] + xv[2]*xv[2] + xv[3]*xv[3];
    #pragma unroll
    for (int off = 1; off < 64; off <<= 1) {
      s  += __shfl_xor(s, off);
      s2 += __shfl_xor(s2, off);
    }
    __shared__ float red[8];
    const int w = tid >> 6;
    if ((tid & 63) == 0) { red[w*2] = s; red[w*2+1] = s2; }
    __syncthreads();
    s  = red[0] + red[2] + red[4] + red[6];
    s2 = red[1] + red[3] + red[5] + red[7];
    const float mu  = s * (1.f / kD);
    const float var = s2 * (1.f / kD) - mu * mu;
    const float rs  = rsqrtf(var + 1e-5f);
    const f32x4 gv = ((const f32x4*)g)[tid];
    const f32x4 bv = ((const f32x4*)bb)[tid];
    bf16x4 o;
    #pragma unroll
    for (int i = 0; i < 4; i++) o[i] = (__bf16)((xv[i] - mu) * rs * gv[i] + bv[i]);
    ((bf16x4*)(hn + (size_t)row * kD))[tid] = o;
  }
}

// ---------------- LayerNorm (layer-1 pre-LN) ----------------
template <bool BF16OUT>
__global__ __launch_bounds__(256) void ln_kernel(const float* __restrict__ x,
                                                 const float* __restrict__ g,
                                                 const float* __restrict__ bb,
                                                 void* __restrict__ outp) {
  const int row = blockIdx.x, tid = threadIdx.x;
  const f32x4 xv = ((const f32x4*)(x + (size_t)row * kD))[tid];
  float s  = xv[0] + xv[1] + xv[2] + xv[3];
  float s2 = xv[0]*xv[0] + xv[1]*xv[1] + xv[2]*xv[2] + xv[3]*xv[3];
  #pragma unroll
  for (int off = 1; off < 64; off <<= 1) {
    s  += __shfl_xor(s, off);
    s2 += __shfl_xor(s2, off);
  }
  __shared__ float red[8];
  const int w = tid >> 6;
  if ((tid & 63) == 0) { red[w*2] = s; red[w*2+1] = s2; }
  __syncthreads();
  s  = red[0] + red[2] + red[4] + red[6];
  s2 = red[1] + red[3] + red[5] + red[7];
  const float mu  = s * (1.f / kD);
  const float var = s2 * (1.f / kD) - mu * mu;
  const float rs  = rsqrtf(var + 1e-5f);
  const f32x4 gv = ((const f32x4*)g)[tid];
  const f32x4 bv = ((const f32x4*)bb)[tid];
  if constexpr (BF16OUT) {
    bf16x4 o;
    #pragma unroll
    for (int i = 0; i < 4; i++) o[i] = (__bf16)((xv[i] - mu) * rs * gv[i] + bv[i]);
    ((bf16x4*)((__bf16*)outp + (size_t)row * kD))[tid] = o;
  } else {
    f32x4 o;
    #pragma unroll
    for (int i = 0; i < 4; i++) o[i] = (xv[i] - mu) * rs * gv[i] + bv[i];
    ((f32x4*)((float*)outp + (size_t)row * kD))[tid] = o;
  }
}

// ---------------- GEMM (m97 structure): C = A @ BT^T + bias ----------------
template <bool OUT_BF16>
__global__ __launch_bounds__(256) void gemm_bt_kernel(const __bf16* __restrict__ A,
                                                      const __bf16* __restrict__ BT,
                                                      const float* __restrict__ bias,
                                                      const float* resid,
                                                      float* outf,
                                                      __bf16* outb,
                                                      __bf16* vtp,
                                                      int N, int K, int ldc, int vt_c0,
                                                      int bm_mult, int bm_add) {
  __shared__ __bf16 As[128 * 64];
  __shared__ __bf16 Bs[128 * 64];
  const int tid = threadIdx.x;
  const int lane = tid & 63, w = tid >> 6;
  int wg = (int)blockIdx.x;
  const int nwg = gridDim.x;
  wg = (wg & 7) * (nwg >> 3) + (wg >> 3);      // bijective XCD swizzle (nwg%8==0)
  const int nbn = N >> 7;
  const int bm = (wg / nbn) * bm_mult + bm_add;
  const int bn = wg % nbn;
  const int wr = (w >> 1) * 64, wc = (w & 1) * 64;
  const int lrow = lane & 15, lk8 = (lane >> 4) * 8;

  const int srow = lane >> 3;
  const int scol = (lane & 7) * 8;
  const __bf16* gA = A + (size_t)(bm * 128) * K;
  const __bf16* gB = BT + (size_t)(bn * 128) * K;

  f32x4 acc[4][4] = {};

  for (int k0 = 0; k0 < K; k0 += 64) {
    __syncthreads();
    #pragma unroll
    for (int i = 0; i < 4; i++) {
      const int c = w * 4 + i;
      const int row = c * 8 + srow;
      gload_lds16(gA + (size_t)row * K + k0 + scol, As + c * 512);
      gload_lds16(gB + (size_t)row * K + k0 + scol, Bs + c * 512);
    }
    __syncthreads();
    #pragma unroll
    for (int ks = 0; ks < 2; ks++) {
      bf16x8 af[4], bf[4];
      #pragma unroll
      for (int mt = 0; mt < 4; mt++)
        af[mt] = *(const bf16x8*)(As + (wr + mt * 16 + lrow) * 64 + ks * 32 + lk8);
      #pragma unroll
      for (int nt = 0; nt < 4; nt++)
        bf[nt] = *(const bf16x8*)(Bs + (wc + nt * 16 + lrow) * 64 + ks * 32 + lk8);
      __builtin_amdgcn_s_setprio(1);
      #pragma unroll
      for (int mt = 0; mt < 4; mt++)
        #pragma unroll
        for (int nt = 0; nt < 4; nt++)
          acc[mt][nt] = MFMA16(af[mt], bf[nt], acc[mt][nt]);
      __builtin_amdgcn_s_setprio(0);
    }
  }

  #pragma unroll
  for (int mt = 0; mt < 4; mt++) {
    const int row0 = bm * 128 + wr + mt * 16 + (lane >> 4) * 4;
    #pragma unroll
    for (int nt = 0; nt < 4; nt++) {
      const int col = bn * 128 + wc + nt * 16 + lrow;
      const float bsv = bias[col];
      if (vtp && col >= vt_c0) {
        const int vd = col - vt_c0;                 // h*64 + d
        const int bb_ = row0 >> 11, t = row0 & (kT - 1);
        bf16x4 pk;
        #pragma unroll
        for (int r = 0; r < 4; r++) pk[r] = (__bf16)(acc[mt][nt][r] + bsv);
        *(bf16x4*)(vtp + ((size_t)((bb_ << 4) + (vd >> 6)) * 64 + (vd & 63)) * kT + t) = pk;
      } else {
        #pragma unroll
        for (int r = 0; r < 4; r++) {
          const size_t idx = (size_t)(row0 + r) * ldc + col;
          const float v = acc[mt][nt][r] + bsv;
          if constexpr (OUT_BF16) {
            outb[idx] = (__bf16)v;
          } else {
            outf[idx] = v + resid[idx];
          }
        }
      }
    }
  }
}

// ---------------- flash attention layer-0: paired q-tiles SHARING one kt loop ----------------
// Block = (bh, sub): q-tiles qt0=sub, qt1=31-sub. One staging pass kt=0..qt1;
// tile applied to acc1 always, to acc0 while kt<=qt0 (block-uniform branch).
// Staging/barriers: 33 -> 32-sub per block (mean -26%). Compute total unchanged.
__global__ __launch_bounds__(256, 4) void flash0_kernel(const __bf16* __restrict__ qkv,
                                                        const __bf16* __restrict__ vtg,
                                                        __bf16* __restrict__ o) {
  constexpr float SC = 0.18033688011112042f;  // (1/8)*log2(e)
  __shared__ __bf16 Ks[64 * 64];
  __shared__ __bf16 Vs[64 * 64];
  const int tid = threadIdx.x, lane = tid & 63, w = tid >> 6;
  int wg = (int)blockIdx.x;
  const int nwg = gridDim.x;
  wg = (wg & 7) * (nwg >> 3) + (wg >> 3);     // XCD swizzle (nwg=1024)
  const int sub = wg & 15, bh = wg >> 4;
  const int b = bh >> 4, hh = bh & 15;
  const int g = lane >> 4, qown = lane & 15;
  const int r8 = lane >> 3;
  const int sslot = (lane & 7) ^ (r8 & 7);    // inverse-swizzled source slot
  const int swz = (qown & 7) << 3;            // read-side XOR (elements)
  const size_t row0 = (size_t)b * kT;
  const int qt0 = sub, qt1 = 31 - sub;

  // both Q fragments direct to registers
  bf16x8 qf0[2], qf1[2];
  {
    const __bf16* qr0p = qkv + (row0 + qt0 * 64 + w * 16 + qown) * kQK + hh * 64;
    const __bf16* qr1p = qkv + (row0 + qt1 * 64 + w * 16 + qown) * kQK + hh * 64;
    #pragma unroll
    for (int ks = 0; ks < 2; ks++) {
      bf16x8 qa = *(const bf16x8*)(qr0p + ks * 32 + 8 * g);
      bf16x8 qb = *(const bf16x8*)(qr1p + ks * 32 + 8 * g);
      #pragma unroll
      for (int i = 0; i < 8; i++) {
        qf0[ks][i] = (__bf16)((float)qa[i] * SC);
        qf1[ks][i] = (__bf16)((float)qb[i] * SC);
      }
    }
  }

  float m0 = -1e30f, l0 = 0.f, m1 = -1e30f, l1 = 0.f;
  f32x4 acc0[4] = {}, acc1[4] = {};

  for (int kt = 0; kt <= qt1; kt++) {
    __syncthreads();   // prior iter's LDS reads done before restage
    #pragma unroll
    for (int j = 0; j < 2; j++) {
      const int r = w * 16 + j * 8 + r8;
      gload_lds16(qkv + (row0 + kt * 64 + r) * kQK + 1024 + hh * 64 + sslot * 8,
                  Ks + (w * 16 + j * 8) * 64);
      gload_lds16(vtg + ((size_t)bh * 64 + r) * kT + kt * 64 + sslot * 8,
                  Vs + (w * 16 + j * 8) * 64);
    }
    __syncthreads();   // K,V landed

    // ======== q-tile 1 (qt1, always active) ========
    {
      f32x4 sv[4] = {};
      #pragma unroll
      for (int nt = 0; nt < 4; nt++) {
        const int kr = nt * 16 + qown;
        #pragma unroll
        for (int ks = 0; ks < 2; ks++) {
          bf16x8 kf = *(const bf16x8*)(Ks + kr * 64 + ((ks * 32 + 8 * g) ^ swz));
          sv[nt] = MFMA16(kf, qf1[ks], sv[nt]);
        }
      }
      if (kt == qt1) {
        #pragma unroll
        for (int nt = 0; nt < 4; nt++)
          #pragma unroll
          for (int r = 0; r < 4; r++)
            if (nt * 16 + 4 * g + r > w * 16 + qown) sv[nt][r] = -1e30f;
      }

      float mx = -1e30f;
      #pragma unroll
      for (int nt = 0; nt < 4; nt++)
        #pragma unroll
        for (int r = 0; r < 4; r++) mx = fmaxf(mx, sv[nt][r]);
      mx = fmaxf(mx, __shfl_xor(mx, 16));
      mx = fmaxf(mx, __shfl_xor(mx, 32));

      float ps = 0.f;
      ull quad[4];
      if (__all(mx - m1 <= 8.0f)) {
        #pragma unroll
        for (int nt = 0; nt < 4; nt++) {
          union { bf16x4 v; ull u; } qd;
          #pragma unroll
          for (int r = 0; r < 4; r++) {
            const float p = exp2f(sv[nt][r] - m1);
            ps += p;
            qd.v[r] = (__bf16)p;
          }
          quad[nt] = qd.u;
        }
        ps += __shfl_xor(ps, 16);
        ps += __shfl_xor(ps, 32);
        l1 += ps;
      } else {
        const float mnew = fmaxf(m1, mx);
        const float fsc = exp2f(m1 - mnew);
        m1 = mnew;
        #pragma unroll
        for (int nt = 0; nt < 4; nt++) {
          union { bf16x4 v; ull u; } qd;
          #pragma unroll
          for (int r = 0; r < 4; r++) {
            const float p = exp2f(sv[nt][r] - mnew);
            ps += p;
            qd.v[r] = (__bf16)p;
          }
          quad[nt] = qd.u;
        }
        ps += __shfl_xor(ps, 16);
        ps += __shfl_xor(ps, 32);
        l1 = l1 * fsc + ps;
        float fr[4];
        #pragma unroll
        for (int r = 0; r < 4; r++) fr[r] = __shfl(fsc, 20 * g + r);
        #pragma unroll
        for (int nt = 0; nt < 4; nt++)
          #pragma unroll
          for (int r = 0; r < 4; r++) acc1[nt][r] *= fr[r];
      }

      bf16x8 pf[2];
      #pragma unroll
      for (int ks = 0; ks < 2; ks++) {
        const int src = (g & 1) * 32 + qown;
        const ull t0 = __shfl(quad[2 * ks],     src);
        const ull t1 = __shfl(quad[2 * ks + 1], src);
        const ull lo = (g & 2) ? t1 : t0;
        const ull t2 = __shfl(quad[2 * ks],     src + 16);
        const ull t3 = __shfl(quad[2 * ks + 1], src + 16);
        const ull hi = (g & 2) ? t3 : t2;
        union { ull u[2]; bf16x8 v; } pk;
        pk.u[0] = lo; pk.u[1] = hi;
        pf[ks] = pk.v;
      }

      #pragma unroll
      for (int nt = 0; nt < 4; nt++) {
        const int vr = nt * 16 + qown;
        #pragma unroll
        for (int ks = 0; ks < 2; ks++) {
          bf16x8 vf = *(const bf16x8*)(Vs + vr * 64 + ((ks * 32 + 8 * g) ^ swz));
          acc1[nt] = MFMA16(pf[ks], vf, acc1[nt]);
        }
      }
    }

    // ======== q-tile 0 (qt0, active while kt <= qt0; block-uniform branch) ========
    if (kt <= qt0) {
      f32x4 sv[4] = {};
      #pragma unroll
      for (int nt = 0; nt < 4; nt++) {
        const int kr = nt * 16 + qown;
        #pragma unroll
        for (int ks = 0; ks < 2; ks++) {
          bf16x8 kf = *(const bf16x8*)(Ks + kr * 64 + ((ks * 32 + 8 * g) ^ swz));
          sv[nt] = MFMA16(kf, qf0[ks], sv[nt]);
        }
      }
      if (kt == qt0) {
        #pragma unroll
        for (int nt = 0; nt < 4; nt++)
          #pragma unroll
          for (int r = 0; r < 4; r++)
            if (nt * 16 + 4 * g + r > w * 16 + qown) sv[nt][r] = -1e30f;
      }

      float mx = -1e30f;
      #pragma unroll
      for (int nt = 0; nt < 4; nt++)
        #pragma unroll
        for (int r = 0; r < 4; r++) mx = fmaxf(mx, sv[nt][r]);
      mx = fmaxf(mx, __shfl_xor(mx, 16));
      mx = fmaxf(mx, __shfl_xor(mx, 32));

      float ps = 0.f;
      ull quad[4];
      if (__all(mx - m0 <= 8.0f)) {
        #pragma unroll
        for (int nt = 0; nt < 4; nt++) {
          union { bf16x4 v; ull u; } qd;
          #pragma unroll
          for (int r = 0; r < 4; r++) {
            const float p = exp2f(sv[nt][r] - m0);
            ps += p;
            qd.v[r] = (__bf16)p;
          }
          quad[nt] = qd.u;
        }
        ps += __shfl_xor(ps, 16);
        ps += __shfl_xor(ps, 32);
        l0 += ps;
      } else {
        const float mnew = fmaxf(m0, mx);
        const float fsc = exp2f(m0 - mnew);
        m0 = mnew;
        #pragma unroll
        for (int nt = 0; nt < 4; nt++) {
          union { bf16x4 v; ull u; } qd;
          #pragma unroll
          for (int r = 0; r < 4; r++) {
            const float p = exp2f(sv[nt][r] - mnew);
            ps += p;
            qd.v[r] = (__bf16)p;
          }
          quad[nt] = qd.u;
        }
        ps += __shfl_xor(ps, 16);
        ps += __shfl_xor(ps, 32);
        l0 = l0 * fsc + ps;
        float fr[4];
        #pragma unroll
        for (int r = 0; r < 4; r++) fr[r] = __shfl(fsc, 20 * g + r);
        #pragma unroll
        for (int nt = 0; nt < 4; nt++)
          #pragma unroll
          for (int r = 0; r < 4; r++) acc0[nt][r] *= fr[r];
      }

      bf16x8 pf[2];
      #pragma unroll
      for (int ks = 0; ks < 2; ks++) {
        const int src = (g & 1) * 32 + qown;
        const ull t0 = __shfl(quad[2 * ks],     src);
        const ull t1 = __shfl(quad[2 * ks + 1], src);
        const ull lo = (g & 2) ? t1 : t0;
        const ull t2 = __shfl(quad[2 * ks],     src + 16);
        const ull t3 = __shfl(quad[2 * ks + 1], src + 16);
        const ull hi = (g & 2) ? t3 : t2;
        union { ull u[2]; bf16x8 v; } pk;
        pk.u[0] = lo; pk.u[1] = hi;
        pf[ks] = pk.v;
      }

      #pragma unroll
      for (int nt = 0; nt < 4; nt++) {
        const int vr = nt * 16 + qown;
        #pragma unroll
        for (int ks = 0; ks < 2; ks++) {
          bf16x8 vf = *(const bf16x8*)(Vs + vr * 64 + ((ks * 32 + 8 * g) ^ swz));
          acc0[nt] = MFMA16(pf[ks], vf, acc0[nt]);
        }
      }
    }
  }  // kt

  // epilogue: write both q-tiles
  {
    const float li = 1.f / l1;
    float lr[4];
    #pragma unroll
    for (int r = 0; r < 4; r++) lr[r] = __shfl(li, 20 * g + r);
    #pragma unroll
    for (int r = 0; r < 4; r++) {
      const int t = qt1 * 64 + w * 16 + 4 * g + r;
      #pragma unroll
      for (int nt = 0; nt < 4; nt++)
        o[(row0 + t) * kD + hh * 64 + nt * 16 + qown] = (__bf16)(acc1[nt][r] * lr[r]);
    }
  }
  {
    const float li = 1.f / l0;
    float lr[4];
    #pragma unroll
    for (int r = 0; r < 4; r++) lr[r] = __shfl(li, 20 * g + r);
    #pragma unroll
    for (int r = 0; r < 4; r++) {
      const int t = qt0 * 64 + w * 16 + 4 * g + r;
      #pragma unroll
      for (int nt = 0; nt < 4; nt++)
        o[(row0 + t) * kD + hh * 64 + nt * 16 + qown] = (__bf16)(acc0[nt][r] * lr[r]);
    }
  }
}

// ---------------- flash layer-1: qt=31, k-chunk split (8x4), f32 partials ----------------
__global__ __launch_bounds__(256) void flash1_kernel(const __bf16* __restrict__ qkv,
                                                     const __bf16* __restrict__ vtg,
                                                     float* __restrict__ part_acc,
                                                     float* __restrict__ part_ml) {
  constexpr float SC = 0.18033688011112042f;
  __shared__ __bf16 Ks[64 * 64];
  __shared__ __bf16 Vs[64 * 64];
  const int tid = threadIdx.x, lane = tid & 63, w = tid >> 6;
  int wg = (int)blockIdx.x;
  const int nwg = gridDim.x;
  wg = (wg & 7) * (nwg >> 3) + (wg >> 3);
  const int sub = wg & 7, bh = wg >> 3;
  const int b = bh >> 4, hh = bh & 15;
  const int g = lane >> 4, qown = lane & 15;
  const int r8 = lane >> 3;
  const int sslot = (lane & 7) ^ (r8 & 7);
  const int swz = (qown & 7) << 3;
  const size_t row0 = (size_t)b * kT;
  const int qt = 31, ktlo = sub * 4, kthi = ktlo + 4;

  const __bf16* qrow = qkv + (row0 + qt * 64 + w * 16 + qown) * kQK + hh * 64;
  bf16x8 qf[2];
  #pragma unroll
  for (int ks = 0; ks < 2; ks++) {
    bf16x8 qr = *(const bf16x8*)(qrow + ks * 32 + 8 * g);
    #pragma unroll
    for (int i = 0; i < 8; i++) qf[ks][i] = (__bf16)((float)qr[i] * SC);
  }

  float m_run = -1e30f, l_run = 0.f;
  f32x4 acc[4] = {};

  for (int kt = ktlo; kt < kthi; kt++) {
    __syncthreads();
    #pragma unroll
    for (int jj = 0; jj < 2; jj++) {
      const int r = w * 16 + jj * 8 + r8;
      gload_lds16(qkv + (row0 + kt * 64 + r) * kQK + 1024 + hh * 64 + sslot * 8,
                  Ks + (w * 16 + jj * 8) * 64);
      gload_lds16(vtg + ((size_t)bh * 64 + r) * kT + kt * 64 + sslot * 8,
                  Vs + (w * 16 + jj * 8) * 64);
    }
    __syncthreads();

    f32x4 sv[4] = {};
    #pragma unroll
    for (int nt = 0; nt < 4; nt++) {
      const int kr = nt * 16 + qown;
      #pragma unroll
      for (int ks = 0; ks < 2; ks++) {
        bf16x8 kf = *(const bf16x8*)(Ks + kr * 64 + ((ks * 32 + 8 * g) ^ swz));
        sv[nt] = MFMA16(kf, qf[ks], sv[nt]);
      }
    }
    if (kt == qt) {
      #pragma unroll
      for (int nt = 0; nt < 4; nt++)
        #pragma unroll
        for (int r = 0; r < 4; r++)
          if (nt * 16 + 4 * g + r > w * 16 + qown) sv[nt][r] = -1e30f;
    }

    float mx = -1e30f;
    #pragma unroll
    for (int nt = 0; nt < 4; nt++)
      #pragma unroll
      for (int r = 0; r < 4; r++) mx = fmaxf(mx, sv[nt][r]);
    mx = fmaxf(mx, __shfl_xor(mx, 16));
    mx = fmaxf(mx, __shfl_xor(mx, 32));

    const float mnew = fmaxf(m_run, mx);
    const float fsc = exp2f(m_run - mnew);
    m_run = mnew;
    float ps = 0.f;
    ull quad[4];
    #pragma unroll
    for (int nt = 0; nt < 4; nt++) {
      union { bf16x4 v; ull u; } qd;
      #pragma unroll
      for (int r = 0; r < 4; r++) {
        const float p = exp2f(sv[nt][r] - mnew);
        ps += p;
        qd.v[r] = (__bf16)p;
      }
      quad[nt] = qd.u;
    }
    ps += __shfl_xor(ps, 16);
    ps += __shfl_xor(ps, 32);
    l_run = l_run * fsc + ps;
    float fr[4];
    #pragma unroll
    for (int r = 0; r < 4; r++) fr[r] = __shfl(fsc, 20 * g + r);
    #pragma unroll
    for (int nt = 0; nt < 4; nt++)
      #pragma unroll
      for (int r = 0; r < 4; r++) acc[nt][r] *= fr[r];

    bf16x8 pf[2];
    #pragma unroll
    for (int ks = 0; ks < 2; ks++) {
      const int src = (g & 1) * 32 + qown;
      const ull t0 = __shfl(quad[2 * ks],     src);
      const ull t1 = __shfl(quad[2 * ks + 1], src);
      const ull lo = (g & 2) ? t1 : t0;
      const ull t2 = __shfl(quad[2 * ks],     src + 16);
      const ull t3 = __shfl(quad[2 * ks + 1], src + 16);
      const ull hi = (g & 2) ? t3 : t2;
      union { ull u[2]; bf16x8 v; } pk;
      pk.u[0] = lo; pk.u[1] = hi;
      pf[ks] = pk.v;
    }

    #pragma unroll
    for (int nt = 0; nt < 4; nt++) {
      const int vr = nt * 16 + qown;
      #pragma unroll
      for (int ks = 0; ks < 2; ks++) {
        bf16x8 vf = *(const bf16x8*)(Vs + vr * 64 + ((ks * 32 + 8 * g) ^ swz));
        acc[nt] = MFMA16(pf[ks], vf, acc[nt]);
      }
    }
  }

  const int tile = bh * 8 + sub;
  #pragma unroll
  for (int r = 0; r < 4; r++) {
    const int rr = w * 16 + 4 * g + r;
    #pragma unroll
    for (int nt = 0; nt < 4; nt++)
      part_acc[(size_t)tile * 4096 + rr * 64 + nt * 16 + qown] = acc[nt][r];
  }
  if (g == 0) {
    part_ml[tile * 128 + w * 16 + qown] = m_run;
    part_ml[tile * 128 + 64 + w * 16 + qown] = l_run;
  }
}

// ---------------- merge k-split flash partials (qt=31, 8 chunks) ----------------
__global__ __launch_bounds__(256) void flash_merge_kernel(const float* __restrict__ part_acc,
                                                          const float* __restrict__ part_ml,
                                                          __bf16* __restrict__ o) {
  const int bh = blockIdx.x, b = bh >> 4, hh = bh & 15;
  for (int e = threadIdx.x; e < 4096; e += 256) {
    const int row = e >> 6, d = e & 63;
    float mstar = -1e30f;
    #pragma unroll
    for (int kc = 0; kc < 8; kc++)
      mstar = fmaxf(mstar, part_ml[(bh * 8 + kc) * 128 + row]);
    float lstar = 0.f, osum = 0.f;
    #pragma unroll
    for (int kc = 0; kc < 8; kc++) {
      const float wgt = exp2f(part_ml[(bh * 8 + kc) * 128 + row] - mstar);
      lstar += wgt * part_ml[(bh * 8 + kc) * 128 + 64 + row];
      osum  += wgt * part_acc[(size_t)(bh * 8 + kc) * 4096 + e];
    }
    o[(size_t)(b * kT + 1984 + row) * kD + hh * 64 + d] = (__bf16)(osum / lstar);
  }
}

// ---------------- layer-2 out-proj, last token only ----------------
__global__ __launch_bounds__(256) void proj_last_kernel(const __bf16* __restrict__ o,
                                                        const float* __restrict__ W,
                                                        const float* __restrict__ bias,
                                                        const float* __restrict__ h,
                                                        float* __restrict__ out4) {
  const int b = blockIdx.y;
  const int j = blockIdx.x * 256 + threadIdx.x;
  __shared__ float ov[kD];
  const __bf16* orow = o + (size_t)(b * kT + kT - 1) * kD;
  for (int i = threadIdx.x; i < kD; i += 256) ov[i] = (float)orow[i];
  __syncthreads();
  float acc = 0.f;
  #pragma unroll 8
  for (int k = 0; k < kD; k++) acc = fmaf(ov[k], W[(size_t)k * kD + j], acc);
  out4[b * kD + j] = h[(size_t)(b * kT + kT - 1) * kD + j] + bias[j] + acc;
}

// ---------------- head: fused final-LN + k-split GEMV ----------------
__global__ __launch_bounds__(256) void head_kernel(const float* __restrict__ hl4,
                                                   const float* __restrict__ g,
                                                   const float* __restrict__ bb,
                                                   const float* __restrict__ W,
                                                   const float* __restrict__ hb,
                                                   float* __restrict__ out) {
  __shared__ float sh[kB * kD];
  __shared__ float red[4][kB][64];
  const int tid = threadIdx.x;
  const int wv = tid >> 6, ln = tid & 63;
  {
    const float* row = hl4 + wv * kD;
    float vals[16];
    float s = 0.f, s2 = 0.f;
    #pragma unroll
    for (int i = 0; i < 16; i++) {
      const float v = row[i * 64 + ln];
      vals[i] = v; s += v; s2 += v * v;
    }
    #pragma unroll
    for (int off = 1; off < 64; off <<= 1) {
      s += __shfl_xor(s, off); s2 += __shfl_xor(s2, off);
    }
    const float mu = s * (1.f / kD);
    const float rs = rsqrtf(s2 * (1.f / kD) - mu * mu + 1e-5f);
    #pragma unroll
    for (int i = 0; i < 16; i++) {
      const int c = i * 64 + ln;
      sh[wv * kD + c] = (vals[i] - mu) * rs * g[c] + bb[c];
    }
  }
  __syncthreads();
  const int jj = tid & 63, ks = tid >> 6;
  const int j = blockIdx.x * 64 + jj;
  float a[kB] = {};
  const int k0 = ks * 256;
  #pragma unroll 4
  for (int k = k0; k < k0 + 256; k++) {
    const float wvw = W[(size_t)k * kC + j];
    #pragma unroll
    for (int b2 = 0; b2 < kB; b2++) a[b2] = fmaf(sh[b2 * kD + k], wvw, a[b2]);
  }
  #pragma unroll
  for (int b2 = 0; b2 < kB; b2++) red[ks][b2][jj] = a[b2];
  __syncthreads();
  if (ks == 0) {
    const float bv = hb[j];
    #pragma unroll
    for (int b2 = 0; b2 < kB; b2++)
      out[(size_t)b2 * kC + j] = red[0][b2][jj] + red[1][b2][jj] + red[2][b2][jj] + red[3][b2][jj] + bv;
  }
}

// ---------------- host ----------------
extern "C" void kernel_launch(void* const* d_in, const int* in_sizes, int n_in,
                              void* d_out, int out_size, void* d_ws, size_t ws_size,
                              hipStream_t stream) {
  const int*   tokens = (const int*)d_in[0];
  const float* embW   = (const float*)d_in[1];
  const float* posW   = (const float*)d_in[2];
  const float* ln_g   = (const float*)d_in[3];
  const float* ln_b   = (const float*)d_in[4];
  const float* qkv_W  = (const float*)d_in[5];
  const float* qkv_b  = (const float*)d_in[6];
  const float* out_W  = (const float*)d_in[7];
  const float* out_b  = (const float*)d_in[8];
  const float* lnf_g  = (const float*)d_in[9];
  const float* lnf_b  = (const float*)d_in[10];
  const float* headW  = (const float*)d_in[11];
  const float* headb  = (const float*)d_in[12];
  float* logits = (float*)d_out;

  char* ws = (char*)d_ws;
  float*  h     = (float*)(ws);                    // [8192][1024] f32   32 MiB
  __bf16* hn    = (__bf16*)(ws + 33554432);        // [8192][1024] bf16  16 MiB
  __bf16* qkv   = (__bf16*)(ws + 50331648);        // [8192][2048] bf16 (Q|K) 32 MiB
  __bf16* Vt    = (__bf16*)(ws + 83886080);        // [64][64][2048] bf16 16 MiB
  __bf16* ob    = (__bf16*)(ws + 100663296);       // [8192][1024] bf16  16 MiB
  __bf16* WqkvT = (__bf16*)(ws + 117440512);       // [2][3072][1024] bf16 12 MiB
  __bf16* WoT   = (__bf16*)(ws + 130613248);       // [1024][1024] bf16 2 MiB
  float*  hl4   = (float*)(ws + 132710400);        // [4][1024]
  float* part_acc = (float*)(ws + 33554432);       // reuse hn region after l1 GEMMs
  float* part_ml  = (float*)(ws + 33554432 + 8388608);

  prep_kernel<<<15360, 256, 0, stream>>>(qkv_W, out_W, WqkvT, WoT,
                                         tokens, embW, posW, ln_g, ln_b, h, hn);

  // ---- layer 0 ----
  gemm_bt_kernel<true><<<(kM/128)*(k3D/128), 256, 0, stream>>>(
      hn, WqkvT, qkv_b, nullptr, nullptr, qkv, Vt, k3D, kD, kQK, 2048, 1, 0);
  flash0_kernel<<<kB*kH*16, 256, 0, stream>>>(qkv, Vt, ob);
  gemm_bt_kernel<false><<<(kM/128)*(kD/128), 256, 0, stream>>>(
      ob, WoT, out_b, h, h, nullptr, nullptr, kD, kD, kD, 1 << 30, 1, 0);

  // ---- layer 1 ----
  ln_kernel<true><<<kM, 256, 0, stream>>>(h, ln_g + kD, ln_b + kD, hn);
  gemm_bt_kernel<true><<<(kM/128)*(2048/128), 256, 0, stream>>>(
      hn, WqkvT + (size_t)k3D*kD + (size_t)kD*kD, qkv_b + k3D + kD,
      nullptr, nullptr, qkv + 1024, Vt, 2048, kD, kQK, 1024, 1, 0);
  gemm_bt_kernel<true><<<kB*(kD/128), 256, 0, stream>>>(
      hn, WqkvT + (size_t)k3D*kD, qkv_b + k3D,
      nullptr, nullptr, qkv, nullptr, kD, kD, kQK, 1 << 30, 16, 15);
  flash1_kernel<<<kB*kH*8, 256, 0, stream>>>(qkv, Vt, part_acc, part_ml);
  flash_merge_kernel<<<kB*kH, 256, 0, stream>>>(part_acc, part_ml, ob);
  proj_last_kernel<<<dim3(kD/256, kB), 256, 0, stream>>>(ob, out_W + (size_t)kD*kD,
                                                         out_b + kD, h, hl4);
  head_kernel<<<kC/64, 256, 0, stream>>>(hl4, lnf_g, lnf_b, headW, headb, logits);
}

// Round 14
// 471.976 us; speedup vs baseline: 1.3217x; 1.3217x over previous
//
#include <hip/hip_runtime.h>

typedef __attribute__((ext_vector_type(8))) __bf16 bf16x8;
typedef __attribute__((ext_vector_type(4))) __bf16 bf16x4;
typedef __attribute__((ext_vector_type(4))) float f32x4;
typedef unsigned long long ull;

static constexpr int kB = 4, kT = 2048, kD = 1024, kH = 16;
static constexpr int kC = 32000, kM = 8192, k3D = 3072, kQK = 2048;

#define MFMA16(a, b, c) __builtin_amdgcn_mfma_f32_16x16x32_bf16((a), (b), (c), 0, 0, 0)

__device__ __forceinline__ void gload_lds16(const __bf16* g, __bf16* l) {
  __builtin_amdgcn_global_load_lds(
      (const __attribute__((address_space(1))) unsigned int*)(const void*)g,
      (__attribute__((address_space(3))) unsigned int*)(void*)l, 16, 0, 0);
}

// ---------------- prep: merged weight transposes + fused embed/LN0 ----------------
__global__ __launch_bounds__(256) void prep_kernel(const float* __restrict__ qkv_W,
                                                   const float* __restrict__ out_W,
                                                   __bf16* __restrict__ WqkvT,
                                                   __bf16* __restrict__ WoT,
                                                   const int* __restrict__ tok,
                                                   const float* __restrict__ embW,
                                                   const float* __restrict__ posW,
                                                   const float* __restrict__ g,
                                                   const float* __restrict__ bb,
                                                   float* __restrict__ h,
                                                   __bf16* __restrict__ hn) {
  const int bid = blockIdx.x, tid = threadIdx.x;
  if (bid < 7168) {
    __shared__ float sh[32][33];
    const float* W; __bf16* WT; int N, tile;
    if (bid < 3072)      { W = qkv_W;                  WT = WqkvT;                  N = k3D; tile = bid; }
    else if (bid < 6144) { W = qkv_W + (size_t)kD*k3D; WT = WqkvT + (size_t)k3D*kD; N = k3D; tile = bid - 3072; }
    else                 { W = out_W;                  WT = WoT;                    N = kD;  tile = bid - 6144; }
    const int tx = tid & 31, ty = tid >> 5;
    const int ntile = N >> 5;
    const int c0 = (tile % ntile) << 5;
    const int r0 = (tile / ntile) << 5;
    #pragma unroll
    for (int i = 0; i < 4; i++) {
      const int r = ty + i * 8;
      sh[r][tx] = W[(size_t)(r0 + r) * N + c0 + tx];
    }
    __syncthreads();
    #pragma unroll
    for (int i = 0; i < 4; i++) {
      const int cc = ty + i * 8;
      WT[(size_t)(c0 + cc) * kD + r0 + tx] = (__bf16)sh[tx][cc];
    }
  } else {
    const int row = bid - 7168;
    const int t = row & (kT - 1);
    const int tk = tok[row];
    const f32x4 e = ((const f32x4*)(embW + (size_t)tk * kD))[tid];
    const f32x4 p = ((const f32x4*)(posW + (size_t)t * kD))[tid];
    const f32x4 xv = e + p;
    ((f32x4*)(h + (size_t)row * kD))[tid] = xv;
    float s  = xv[0] + xv[1] + xv[2] + xv[3];
    float s2 = xv[0]*xv[0] + xv[1]*xv[1] + xv[2]*xv[2] + xv[3]*xv[3];
    #pragma unroll
    for (int off = 1; off < 64; off <<= 1) {
      s  += __shfl_xor(s, off);
      s2 += __shfl_xor(s2, off);
    }
    __shared__ float red[8];
    const int w = tid >> 6;
    if ((tid & 63) == 0) { red[w*2] = s; red[w*2+1] = s2; }
    __syncthreads();
    s  = red[0] + red[2] + red[4] + red[6];
    s2 = red[1] + red[3] + red[5] + red[7];
    const float mu  = s * (1.f / kD);
    const float var = s2 * (1.f / kD) - mu * mu;
    const float rs  = rsqrtf(var + 1e-5f);
    const f32x4 gv = ((const f32x4*)g)[tid];
    const f32x4 bv = ((const f32x4*)bb)[tid];
    bf16x4 o;
    #pragma unroll
    for (int i = 0; i < 4; i++) o[i] = (__bf16)((xv[i] - mu) * rs * gv[i] + bv[i]);
    ((bf16x4*)(hn + (size_t)row * kD))[tid] = o;
  }
}

// ---------------- LayerNorm (layer-1 pre-LN) ----------------
template <bool BF16OUT>
__global__ __launch_bounds__(256) void ln_kernel(const float* __restrict__ x,
                                                 const float* __restrict__ g,
                                                 const float* __restrict__ bb,
                                                 void* __restrict__ outp) {
  const int row = blockIdx.x, tid = threadIdx.x;
  const f32x4 xv = ((const f32x4*)(x + (size_t)row * kD))[tid];
  float s  = xv[0] + xv[1] + xv[2] + xv[3];
  float s2 = xv[0]*xv[0] + xv[1]*xv[1] + xv[2]*xv[2] + xv[3]*xv[3];
  #pragma unroll
  for (int off = 1; off < 64; off <<= 1) {
    s  += __shfl_xor(s, off);
    s2 += __shfl_xor(s2, off);
  }
  __shared__ float red[8];
  const int w = tid >> 6;
  if ((tid & 63) == 0) { red[w*2] = s; red[w*2+1] = s2; }
  __syncthreads();
  s  = red[0] + red[2] + red[4] + red[6];
  s2 = red[1] + red[3] + red[5] + red[7];
  const float mu  = s * (1.f / kD);
  const float var = s2 * (1.f / kD) - mu * mu;
  const float rs  = rsqrtf(var + 1e-5f);
  const f32x4 gv = ((const f32x4*)g)[tid];
  const f32x4 bv = ((const f32x4*)bb)[tid];
  if constexpr (BF16OUT) {
    bf16x4 o;
    #pragma unroll
    for (int i = 0; i < 4; i++) o[i] = (__bf16)((xv[i] - mu) * rs * gv[i] + bv[i]);
    ((bf16x4*)((__bf16*)outp + (size_t)row * kD))[tid] = o;
  } else {
    f32x4 o;
    #pragma unroll
    for (int i = 0; i < 4; i++) o[i] = (xv[i] - mu) * rs * gv[i] + bv[i];
    ((f32x4*)((float*)outp + (size_t)row * kD))[tid] = o;
  }
}

// ---------------- GEMM (m97 structure): C = A @ BT^T + bias ----------------
template <bool OUT_BF16>
__global__ __launch_bounds__(256) void gemm_bt_kernel(const __bf16* __restrict__ A,
                                                      const __bf16* __restrict__ BT,
                                                      const float* __restrict__ bias,
                                                      const float* resid,
                                                      float* outf,
                                                      __bf16* outb,
                                                      __bf16* vtp,
                                                      int N, int K, int ldc, int vt_c0,
                                                      int bm_mult, int bm_add) {
  __shared__ __bf16 As[128 * 64];
  __shared__ __bf16 Bs[128 * 64];
  const int tid = threadIdx.x;
  const int lane = tid & 63, w = tid >> 6;
  int wg = (int)blockIdx.x;
  const int nwg = gridDim.x;
  wg = (wg & 7) * (nwg >> 3) + (wg >> 3);      // bijective XCD swizzle (nwg%8==0)
  const int nbn = N >> 7;
  const int bm = (wg / nbn) * bm_mult + bm_add;
  const int bn = wg % nbn;
  const int wr = (w >> 1) * 64, wc = (w & 1) * 64;
  const int lrow = lane & 15, lk8 = (lane >> 4) * 8;

  const int srow = lane >> 3;
  const int scol = (lane & 7) * 8;
  const __bf16* gA = A + (size_t)(bm * 128) * K;
  const __bf16* gB = BT + (size_t)(bn * 128) * K;

  f32x4 acc[4][4] = {};

  for (int k0 = 0; k0 < K; k0 += 64) {
    __syncthreads();
    #pragma unroll
    for (int i = 0; i < 4; i++) {
      const int c = w * 4 + i;
      const int row = c * 8 + srow;
      gload_lds16(gA + (size_t)row * K + k0 + scol, As + c * 512);
      gload_lds16(gB + (size_t)row * K + k0 + scol, Bs + c * 512);
    }
    __syncthreads();
    #pragma unroll
    for (int ks = 0; ks < 2; ks++) {
      bf16x8 af[4], bf[4];
      #pragma unroll
      for (int mt = 0; mt < 4; mt++)
        af[mt] = *(const bf16x8*)(As + (wr + mt * 16 + lrow) * 64 + ks * 32 + lk8);
      #pragma unroll
      for (int nt = 0; nt < 4; nt++)
        bf[nt] = *(const bf16x8*)(Bs + (wc + nt * 16 + lrow) * 64 + ks * 32 + lk8);
      __builtin_amdgcn_s_setprio(1);
      #pragma unroll
      for (int mt = 0; mt < 4; mt++)
        #pragma unroll
        for (int nt = 0; nt < 4; nt++)
          acc[mt][nt] = MFMA16(af[mt], bf[nt], acc[mt][nt]);
      __builtin_amdgcn_s_setprio(0);
    }
  }

  #pragma unroll
  for (int mt = 0; mt < 4; mt++) {
    const int row0 = bm * 128 + wr + mt * 16 + (lane >> 4) * 4;
    #pragma unroll
    for (int nt = 0; nt < 4; nt++) {
      const int col = bn * 128 + wc + nt * 16 + lrow;
      const float bsv = bias[col];
      if (vtp && col >= vt_c0) {
        const int vd = col - vt_c0;                 // h*64 + d
        const int bb_ = row0 >> 11, t = row0 & (kT - 1);
        bf16x4 pk;
        #pragma unroll
        for (int r = 0; r < 4; r++) pk[r] = (__bf16)(acc[mt][nt][r] + bsv);
        *(bf16x4*)(vtp + ((size_t)((bb_ << 4) + (vd >> 6)) * 64 + (vd & 63)) * kT + t) = pk;
      } else {
        #pragma unroll
        for (int r = 0; r < 4; r++) {
          const size_t idx = (size_t)(row0 + r) * ldc + col;
          const float v = acc[mt][nt][r] + bsv;
          if constexpr (OUT_BF16) {
            outb[idx] = (__bf16)v;
          } else {
            outf[idx] = v + resid[idx];
          }
        }
      }
    }
  }
}

// ---------------- flash attention layer-0 (r8-proven structure) ----------------
__global__ __launch_bounds__(256) void flash0_kernel(const __bf16* __restrict__ qkv,
                                                     const __bf16* __restrict__ vtg,
                                                     __bf16* __restrict__ o) {
  constexpr float SC = 0.18033688011112042f;  // (1/8)*log2(e)
  __shared__ __bf16 Ks[64 * 64];
  __shared__ __bf16 Vs[64 * 64];
  const int tid = threadIdx.x, lane = tid & 63, w = tid >> 6;
  int wg = (int)blockIdx.x;
  const int nwg = gridDim.x;
  wg = (wg & 7) * (nwg >> 3) + (wg >> 3);     // XCD swizzle (nwg=1024)
  const int sub = wg & 15, bh = wg >> 4;
  const int b = bh >> 4, hh = bh & 15;
  const int g = lane >> 4, qown = lane & 15;
  const int r8 = lane >> 3;
  const int sslot = (lane & 7) ^ (r8 & 7);    // inverse-swizzled source slot
  const int swz = (qown & 7) << 3;            // read-side XOR (elements)
  const size_t row0 = (size_t)b * kT;

  for (int s = 0; s < 2; s++) {
    const int qt = s ? (31 - sub) : sub;

    const __bf16* qrow = qkv + (row0 + qt * 64 + w * 16 + qown) * kQK + hh * 64;
    bf16x8 qf[2];
    #pragma unroll
    for (int ks = 0; ks < 2; ks++) {
      bf16x8 qr = *(const bf16x8*)(qrow + ks * 32 + 8 * g);
      #pragma unroll
      for (int i = 0; i < 8; i++) qf[ks][i] = (__bf16)((float)qr[i] * SC);
    }

    float m_run = -1e30f, l_run = 0.f;
    f32x4 acc[4] = {};

    for (int kt = 0; kt <= qt; kt++) {
      __syncthreads();   // prior iter's LDS reads done before restage
      #pragma unroll
      for (int j = 0; j < 2; j++) {
        const int r = w * 16 + j * 8 + r8;
        gload_lds16(qkv + (row0 + kt * 64 + r) * kQK + 1024 + hh * 64 + sslot * 8,
                    Ks + (w * 16 + j * 8) * 64);
        gload_lds16(vtg + ((size_t)bh * 64 + r) * kT + kt * 64 + sslot * 8,
                    Vs + (w * 16 + j * 8) * 64);
      }
      __syncthreads();   // K,V landed

      f32x4 sv[4] = {};
      #pragma unroll
      for (int nt = 0; nt < 4; nt++) {
        const int kr = nt * 16 + qown;
        #pragma unroll
        for (int ks = 0; ks < 2; ks++) {
          bf16x8 kf = *(const bf16x8*)(Ks + kr * 64 + ((ks * 32 + 8 * g) ^ swz));
          sv[nt] = MFMA16(kf, qf[ks], sv[nt]);
        }
      }
      if (kt == qt) {
        #pragma unroll
        for (int nt = 0; nt < 4; nt++)
          #pragma unroll
          for (int r = 0; r < 4; r++)
            if (nt * 16 + 4 * g + r > w * 16 + qown) sv[nt][r] = -1e30f;
      }

      float mx = -1e30f;
      #pragma unroll
      for (int nt = 0; nt < 4; nt++)
        #pragma unroll
        for (int r = 0; r < 4; r++) mx = fmaxf(mx, sv[nt][r]);
      mx = fmaxf(mx, __shfl_xor(mx, 16));
      mx = fmaxf(mx, __shfl_xor(mx, 32));

      float ps = 0.f;
      ull quad[4];
      if (__all(mx - m_run <= 8.0f)) {
        #pragma unroll
        for (int nt = 0; nt < 4; nt++) {
          union { bf16x4 v; ull u; } qd;
          #pragma unroll
          for (int r = 0; r < 4; r++) {
            const float p = exp2f(sv[nt][r] - m_run);
            ps += p;
            qd.v[r] = (__bf16)p;
          }
          quad[nt] = qd.u;
        }
        ps += __shfl_xor(ps, 16);
        ps += __shfl_xor(ps, 32);
        l_run += ps;
      } else {
        const float mnew = fmaxf(m_run, mx);
        const float fsc = exp2f(m_run - mnew);
        m_run = mnew;
        #pragma unroll
        for (int nt = 0; nt < 4; nt++) {
          union { bf16x4 v; ull u; } qd;
          #pragma unroll
          for (int r = 0; r < 4; r++) {
            const float p = exp2f(sv[nt][r] - mnew);
            ps += p;
            qd.v[r] = (__bf16)p;
          }
          quad[nt] = qd.u;
        }
        ps += __shfl_xor(ps, 16);
        ps += __shfl_xor(ps, 32);
        l_run = l_run * fsc + ps;
        float fr[4];
        #pragma unroll
        for (int r = 0; r < 4; r++) fr[r] = __shfl(fsc, 20 * g + r);
        #pragma unroll
        for (int nt = 0; nt < 4; nt++)
          #pragma unroll
          for (int r = 0; r < 4; r++) acc[nt][r] *= fr[r];
      }

      bf16x8 pf[2];
      #pragma unroll
      for (int ks = 0; ks < 2; ks++) {
        const int src = (g & 1) * 32 + qown;
        const ull t0 = __shfl(quad[2 * ks],     src);
        const ull t1 = __shfl(quad[2 * ks + 1], src);
        const ull lo = (g & 2) ? t1 : t0;
        const ull t2 = __shfl(quad[2 * ks],     src + 16);
        const ull t3 = __shfl(quad[2 * ks + 1], src + 16);
        const ull hi = (g & 2) ? t3 : t2;
        union { ull u[2]; bf16x8 v; } pk;
        pk.u[0] = lo; pk.u[1] = hi;
        pf[ks] = pk.v;
      }

      #pragma unroll
      for (int nt = 0; nt < 4; nt++) {
        const int vr = nt * 16 + qown;
        #pragma unroll
        for (int ks = 0; ks < 2; ks++) {
          bf16x8 vf = *(const bf16x8*)(Vs + vr * 64 + ((ks * 32 + 8 * g) ^ swz));
          acc[nt] = MFMA16(pf[ks], vf, acc[nt]);
        }
      }
    }  // kt

    const float li = 1.f / l_run;
    float lr[4];
    #pragma unroll
    for (int r = 0; r < 4; r++) lr[r] = __shfl(li, 20 * g + r);
    #pragma unroll
    for (int r = 0; r < 4; r++) {
      const int t = qt * 64 + w * 16 + 4 * g + r;
      #pragma unroll
      for (int nt = 0; nt < 4; nt++)
        o[(row0 + t) * kD + hh * 64 + nt * 16 + qown] = (__bf16)(acc[nt][r] * lr[r]);
    }
  }  // s
}

// ---------------- flash layer-1: qt=31, k-chunk split, f32 partials ----------------
__global__ __launch_bounds__(256) void flash1_kernel(const __bf16* __restrict__ qkv,
                                                     const __bf16* __restrict__ vtg,
                                                     float* __restrict__ part_acc,
                                                     float* __restrict__ part_ml) {
  constexpr float SC = 0.18033688011112042f;
  __shared__ __bf16 Ks[64 * 64];
  __shared__ __bf16 Vs[64 * 64];
  const int tid = threadIdx.x, lane = tid & 63, w = tid >> 6;
  int wg = (int)blockIdx.x;
  const int nwg = gridDim.x;
  wg = (wg & 7) * (nwg >> 3) + (wg >> 3);
  const int sub = wg & 7, bh = wg >> 3;
  const int b = bh >> 4, hh = bh & 15;
  const int g = lane >> 4, qown = lane & 15;
  const int r8 = lane >> 3;
  const int sslot = (lane & 7) ^ (r8 & 7);
  const int swz = (qown & 7) << 3;
  const size_t row0 = (size_t)b * kT;
  const int qt = 31, ktlo = sub * 4, kthi = ktlo + 4;

  const __bf16* qrow = qkv + (row0 + qt * 64 + w * 16 + qown) * kQK + hh * 64;
  bf16x8 qf[2];
  #pragma unroll
  for (int ks = 0; ks < 2; ks++) {
    bf16x8 qr = *(const bf16x8*)(qrow + ks * 32 + 8 * g);
    #pragma unroll
    for (int i = 0; i < 8; i++) qf[ks][i] = (__bf16)((float)qr[i] * SC);
  }

  float m_run = -1e30f, l_run = 0.f;
  f32x4 acc[4] = {};

  for (int kt = ktlo; kt < kthi; kt++) {
    __syncthreads();
    #pragma unroll
    for (int jj = 0; jj < 2; jj++) {
      const int r = w * 16 + jj * 8 + r8;
      gload_lds16(qkv + (row0 + kt * 64 + r) * kQK + 1024 + hh * 64 + sslot * 8,
                  Ks + (w * 16 + jj * 8) * 64);
      gload_lds16(vtg + ((size_t)bh * 64 + r) * kT + kt * 64 + sslot * 8,
                  Vs + (w * 16 + jj * 8) * 64);
    }
    __syncthreads();

    f32x4 sv[4] = {};
    #pragma unroll
    for (int nt = 0; nt < 4; nt++) {
      const int kr = nt * 16 + qown;
      #pragma unroll
      for (int ks = 0; ks < 2; ks++) {
        bf16x8 kf = *(const bf16x8*)(Ks + kr * 64 + ((ks * 32 + 8 * g) ^ swz));
        sv[nt] = MFMA16(kf, qf[ks], sv[nt]);
      }
    }
    if (kt == qt) {
      #pragma unroll
      for (int nt = 0; nt < 4; nt++)
        #pragma unroll
        for (int r = 0; r < 4; r++)
          if (nt * 16 + 4 * g + r > w * 16 + qown) sv[nt][r] = -1e30f;
    }

    float mx = -1e30f;
    #pragma unroll
    for (int nt = 0; nt < 4; nt++)
      #pragma unroll
      for (int r = 0; r < 4; r++) mx = fmaxf(mx, sv[nt][r]);
    mx = fmaxf(mx, __shfl_xor(mx, 16));
    mx = fmaxf(mx, __shfl_xor(mx, 32));

    const float mnew = fmaxf(m_run, mx);
    const float fsc = exp2f(m_run - mnew);
    m_run = mnew;
    float ps = 0.f;
    ull quad[4];
    #pragma unroll
    for (int nt = 0; nt < 4; nt++) {
      union { bf16x4 v; ull u; } qd;
      #pragma unroll
      for (int r = 0; r < 4; r++) {
        const float p = exp2f(sv[nt][r] - mnew);
        ps += p;
        qd.v[r] = (__bf16)p;
      }
      quad[nt] = qd.u;
    }
    ps += __shfl_xor(ps, 16);
    ps += __shfl_xor(ps, 32);
    l_run = l_run * fsc + ps;
    float fr[4];
    #pragma unroll
    for (int r = 0; r < 4; r++) fr[r] = __shfl(fsc, 20 * g + r);
    #pragma unroll
    for (int nt = 0; nt < 4; nt++)
      #pragma unroll
      for (int r = 0; r < 4; r++) acc[nt][r] *= fr[r];

    bf16x8 pf[2];
    #pragma unroll
    for (int ks = 0; ks < 2; ks++) {
      const int src = (g & 1) * 32 + qown;
      const ull t0 = __shfl(quad[2 * ks],     src);
      const ull t1 = __shfl(quad[2 * ks + 1], src);
      const ull lo = (g & 2) ? t1 : t0;
      const ull t2 = __shfl(quad[2 * ks],     src + 16);
      const ull t3 = __shfl(quad[2 * ks + 1], src + 16);
      const ull hi = (g & 2) ? t3 : t2;
      union { ull u[2]; bf16x8 v; } pk;
      pk.u[0] = lo; pk.u[1] = hi;
      pf[ks] = pk.v;
    }

    #pragma unroll
    for (int nt = 0; nt < 4; nt++) {
      const int vr = nt * 16 + qown;
      #pragma unroll
      for (int ks = 0; ks < 2; ks++) {
        bf16x8 vf = *(const bf16x8*)(Vs + vr * 64 + ((ks * 32 + 8 * g) ^ swz));
        acc[nt] = MFMA16(pf[ks], vf, acc[nt]);
      }
    }
  }

  const int tile = bh * 8 + sub;
  #pragma unroll
  for (int r = 0; r < 4; r++) {
    const int rr = w * 16 + 4 * g + r;
    #pragma unroll
    for (int nt = 0; nt < 4; nt++)
      part_acc[(size_t)tile * 4096 + rr * 64 + nt * 16 + qown] = acc[nt][r];
  }
  if (g == 0) {
    part_ml[tile * 128 + w * 16 + qown] = m_run;
    part_ml[tile * 128 + 64 + w * 16 + qown] = l_run;
  }
}

// ---------------- merge k-split flash partials (qt=31) ----------------
__global__ __launch_bounds__(256) void flash_merge_kernel(const float* __restrict__ part_acc,
                                                          const float* __restrict__ part_ml,
                                                          __bf16* __restrict__ o) {
  const int bh = blockIdx.x, b = bh >> 4, hh = bh & 15;
  for (int e = threadIdx.x; e < 4096; e += 256) {
    const int row = e >> 6, d = e & 63;
    float mstar = -1e30f;
    #pragma unroll
    for (int kc = 0; kc < 8; kc++)
      mstar = fmaxf(mstar, part_ml[(bh * 8 + kc) * 128 + row]);
    float lstar = 0.f, osum = 0.f;
    #pragma unroll
    for (int kc = 0; kc < 8; kc++) {
      const float wgt = exp2f(part_ml[(bh * 8 + kc) * 128 + row] - mstar);
      lstar += wgt * part_ml[(bh * 8 + kc) * 128 + 64 + row];
      osum  += wgt * part_acc[(size_t)(bh * 8 + kc) * 4096 + e];
    }
    o[(size_t)(b * kT + 1984 + row) * kD + hh * 64 + d] = (__bf16)(osum / lstar);
  }
}

// ---------------- layer-2 out-proj, last token only ----------------
__global__ __launch_bounds__(256) void proj_last_kernel(const __bf16* __restrict__ o,
                                                        const float* __restrict__ W,
                                                        const float* __restrict__ bias,
                                                        const float* __restrict__ h,
                                                        float* __restrict__ out4) {
  const int b = blockIdx.y;
  const int j = blockIdx.x * 256 + threadIdx.x;
  __shared__ float ov[kD];
  const __bf16* orow = o + (size_t)(b * kT + kT - 1) * kD;
  for (int i = threadIdx.x; i < kD; i += 256) ov[i] = (float)orow[i];
  __syncthreads();
  float acc = 0.f;
  #pragma unroll 8
  for (int k = 0; k < kD; k++) acc = fmaf(ov[k], W[(size_t)k * kD + j], acc);
  out4[b * kD + j] = h[(size_t)(b * kT + kT - 1) * kD + j] + bias[j] + acc;
}

// ---------------- head: fused final-LN + k-split GEMV ----------------
__global__ __launch_bounds__(256) void head_kernel(const float* __restrict__ hl4,
                                                   const float* __restrict__ g,
                                                   const float* __restrict__ bb,
                                                   const float* __restrict__ W,
                                                   const float* __restrict__ hb,
                                                   float* __restrict__ out) {
  __shared__ float sh[kB * kD];
  __shared__ float red[4][kB][64];
  const int tid = threadIdx.x;
  const int wv = tid >> 6, ln = tid & 63;
  {
    const float* row = hl4 + wv * kD;
    float vals[16];
    float s = 0.f, s2 = 0.f;
    #pragma unroll
    for (int i = 0; i < 16; i++) {
      const float v = row[i * 64 + ln];
      vals[i] = v; s += v; s2 += v * v;
    }
    #pragma unroll
    for (int off = 1; off < 64; off <<= 1) {
      s += __shfl_xor(s, off); s2 += __shfl_xor(s2, off);
    }
    const float mu = s * (1.f / kD);
    const float rs = rsqrtf(s2 * (1.f / kD) - mu * mu + 1e-5f);
    #pragma unroll
    for (int i = 0; i < 16; i++) {
      const int c = i * 64 + ln;
      sh[wv * kD + c] = (vals[i] - mu) * rs * g[c] + bb[c];
    }
  }
  __syncthreads();
  const int jj = tid & 63, ks = tid >> 6;
  const int j = blockIdx.x * 64 + jj;
  float a[kB] = {};
  const int k0 = ks * 256;
  #pragma unroll 4
  for (int k = k0; k < k0 + 256; k++) {
    const float wvw = W[(size_t)k * kC + j];
    #pragma unroll
    for (int b2 = 0; b2 < kB; b2++) a[b2] = fmaf(sh[b2 * kD + k], wvw, a[b2]);
  }
  #pragma unroll
  for (int b2 = 0; b2 < kB; b2++) red[ks][b2][jj] = a[b2];
  __syncthreads();
  if (ks == 0) {
    const float bv = hb[j];
    #pragma unroll
    for (int b2 = 0; b2 < kB; b2++)
      out[(size_t)b2 * kC + j] = red[0][b2][jj] + red[1][b2][jj] + red[2][b2][jj] + red[3][b2][jj] + bv;
  }
}

// ---------------- host ----------------
extern "C" void kernel_launch(void* const* d_in, const int* in_sizes, int n_in,
                              void* d_out, int out_size, void* d_ws, size_t ws_size,
                              hipStream_t stream) {
  const int*   tokens = (const int*)d_in[0];
  const float* embW   = (const float*)d_in[1];
  const float* posW   = (const float*)d_in[2];
  const float* ln_g   = (const float*)d_in[3];
  const float* ln_b   = (const float*)d_in[4];
  const float* qkv_W  = (const float*)d_in[5];
  const float* qkv_b  = (const float*)d_in[6];
  const float* out_W  = (const float*)d_in[7];
  const float* out_b  = (const float*)d_in[8];
  const float* lnf_g  = (const float*)d_in[9];
  const float* lnf_b  = (const float*)d_in[10];
  const float* headW  = (const float*)d_in[11];
  const float* headb  = (const float*)d_in[12];
  float* logits = (float*)d_out;

  char* ws = (char*)d_ws;
  float*  h     = (float*)(ws);                    // [8192][1024] f32   32 MiB
  __bf16* hn    = (__bf16*)(ws + 33554432);        // [8192][1024] bf16  16 MiB
  __bf16* qkv   = (__bf16*)(ws + 50331648);        // [8192][2048] bf16 (Q|K) 32 MiB
  __bf16* Vt    = (__bf16*)(ws + 83886080);        // [64][64][2048] bf16 16 MiB
  __bf16* ob    = (__bf16*)(ws + 100663296);       // [8192][1024] bf16  16 MiB
  __bf16* WqkvT = (__bf16*)(ws + 117440512);       // [2][3072][1024] bf16 12 MiB
  __bf16* WoT   = (__bf16*)(ws + 130613248);       // [1024][1024] bf16 2 MiB
  float*  hl4   = (float*)(ws + 132710400);        // [4][1024]
  float* part_acc = (float*)(ws + 33554432);       // reuse hn region after l1 GEMMs
  float* part_ml  = (float*)(ws + 33554432 + 8388608);

  prep_kernel<<<15360, 256, 0, stream>>>(qkv_W, out_W, WqkvT, WoT,
                                         tokens, embW, posW, ln_g, ln_b, h, hn);

  // ---- layer 0 ----
  gemm_bt_kernel<true><<<(kM/128)*(k3D/128), 256, 0, stream>>>(
      hn, WqkvT, qkv_b, nullptr, nullptr, qkv, Vt, k3D, kD, kQK, 2048, 1, 0);
  flash0_kernel<<<kB*kH*16, 256, 0, stream>>>(qkv, Vt, ob);
  gemm_bt_kernel<false><<<(kM/128)*(kD/128), 256, 0, stream>>>(
      ob, WoT, out_b, h, h, nullptr, nullptr, kD, kD, kD, 1 << 30, 1, 0);

  // ---- layer 1 ----
  ln_kernel<true><<<kM, 256, 0, stream>>>(h, ln_g + kD, ln_b + kD, hn);
  gemm_bt_kernel<true><<<(kM/128)*(2048/128), 256, 0, stream>>>(
      hn, WqkvT + (size_t)k3D*kD + (size_t)kD*kD, qkv_b + k3D + kD,
      nullptr, nullptr, qkv + 1024, Vt, 2048, kD, kQK, 1024, 1, 0);
  gemm_bt_kernel<true><<<kB*(kD/128), 256, 0, stream>>>(
      hn, WqkvT + (size_t)k3D*kD, qkv_b + k3D,
      nullptr, nullptr, qkv, nullptr, kD, kD, kQK, 1 << 30, 16, 15);
  flash1_kernel<<<kB*kH*8, 256, 0, stream>>>(qkv, Vt, part_acc, part_ml);
  flash_merge_kernel<<<kB*kH, 256, 0, stream>>>(part_acc, part_ml, ob);
  proj_last_kernel<<<dim3(kD/256, kB), 256, 0, stream>>>(ob, out_W + (size_t)kD*kD,
                                                         out_b + kD, h, hl4);
  head_kernel<<<kC/64, 256, 0, stream>>>(hl4, lnf_g, lnf_b, headW, headb, logits);
}